// Round 3
// baseline (2964.352 us; speedup 1.0000x reference)
//
#include <hip/hip_runtime.h>

// BiMPNN layer, MI355X. f32 I/O, bf16 MFMA internally.
//   agg  = A  @ (h@W^T  + b)  ==  (A @ h) @ W^T  + deg_out * b   (linearity)
//   aggt = A^T@ (h@Wt^T + bt) ==  (A^T@ h) @ Wt^T + deg_in  * bt
// R3: exact CSR replaced by 128-node bucket binning (fixed-capacity, packed u32),
// bucket-parallel LDS-accumulator aggregation (ds_add_f32), degrees via LDS count.
// Rationale: R2's k_fill showed 203MB WRITE_SIZE (16x amplification from random
// 4B scatter) at 300us; bucketed cursors keep writes line-local.

typedef __bf16 bf16;
typedef __bf16 bf16x2 __attribute__((ext_vector_type(2)));
typedef __bf16 bf16x4 __attribute__((ext_vector_type(4)));
typedef __bf16 bf16x8 __attribute__((ext_vector_type(8)));
typedef float  f32x4  __attribute__((ext_vector_type(4)));
typedef unsigned int u32;

#define D 128
#define BKT_CAP 2432   // mean edges/bucket = 1.6M/782 = 2046, +8.5 sigma

__global__ void k_cast(const float* __restrict__ src, bf16* __restrict__ dst, int n4) {
    int i = blockIdx.x * 256 + threadIdx.x;
    if (i < n4) {
        f32x4 v = *(const f32x4*)&src[i * 4];
        bf16x4 o;
        o.x = (bf16)v.x; o.y = (bf16)v.y; o.z = (bf16)v.z; o.w = (bf16)v.w;
        *(bf16x4*)&dst[i * 4] = o;
    }
}

// Bin edges into 128-node buckets, both directions in one pass.
// packed word: (node & 127) << 17 | src   (src < 131072 = 2^17)
__global__ void k_bin(const int* __restrict__ rows, const int* __restrict__ cols,
                      int* __restrict__ cnt_f, int* __restrict__ cnt_r,
                      u32* __restrict__ buf_f, u32* __restrict__ buf_r, int E) {
    int e = blockIdx.x * 256 + threadIdx.x;
    if (e < E) {
        int r = rows[e], c = cols[e];
        int p = atomicAdd(&cnt_f[r >> 7], 1);
        if (p < BKT_CAP)
            buf_f[(size_t)(r >> 7) * BKT_CAP + p] = ((u32)(r & 127) << 17) | (u32)c;
        int q = atomicAdd(&cnt_r[c >> 7], 1);
        if (q < BKT_CAP)
            buf_r[(size_t)(c >> 7) * BKT_CAP + q] = ((u32)(c & 127) << 17) | (u32)r;
    }
}

// One block per (bucket, direction). 128 nodes x 128 feats f32 accumulator in LDS.
// Feature f stored at LDS col perm(f): even f -> f/2, odd f -> 64+f/2, so the two
// ds_add_f32 per lane hit banks lane%32 (2-way aliasing = free).
__global__ __launch_bounds__(256) void k_agg(
    const bf16* __restrict__ h,
    const int* __restrict__ cnt_f, const int* __restrict__ cnt_r,
    const u32* __restrict__ buf_f, const u32* __restrict__ buf_r,
    bf16* __restrict__ AH, bf16* __restrict__ ATH,
    int* __restrict__ deg_out, int* __restrict__ deg_in, int N) {
    __shared__ float acc[128 * 128];   // 64 KB
    __shared__ int degs[128];
    int t = threadIdx.x, lane = t & 63, w = t >> 6;
    int bkt = blockIdx.x;

    const u32* buf; int cnt; bf16* dst; int* deg;
    if (blockIdx.y == 0) {
        buf = buf_f + (size_t)bkt * BKT_CAP; cnt = cnt_f[bkt]; dst = AH;  deg = deg_out;
    } else {
        buf = buf_r + (size_t)bkt * BKT_CAP; cnt = cnt_r[bkt]; dst = ATH; deg = deg_in;
    }
    if (cnt > BKT_CAP) cnt = BKT_CAP;

    f32x4* a4 = (f32x4*)acc;
    for (int i = t; i < 4096; i += 256) a4[i] = (f32x4){0.f, 0.f, 0.f, 0.f};
    if (t < 128) degs[t] = 0;
    __syncthreads();

    const bf16x2* h2 = (const bf16x2*)h;
    const int U = 8;
    for (int base = w * U; base < cnt; base += 4 * U) {
        int m = cnt - base;             // wave-uniform
        u32 pk[U]; bf16x2 v[U];
#pragma unroll
        for (int u = 0; u < U; ++u) if (u < m) pk[u] = buf[base + u];
#pragma unroll
        for (int u = 0; u < U; ++u) if (u < m)
            v[u] = h2[(size_t)(pk[u] & 0x1FFFF) * 64 + lane];
#pragma unroll
        for (int u = 0; u < U; ++u) if (u < m) {
            int row = (int)(pk[u] >> 17);
            atomicAdd(&acc[row * 128 + lane],      (float)v[u].x);
            atomicAdd(&acc[row * 128 + 64 + lane], (float)v[u].y);
            if (lane == 0) atomicAdd(&degs[row], 1);
        }
    }
    __syncthreads();

    int node0 = bkt * 128;
#pragma unroll 4
    for (int rr = 0; rr < 32; ++rr) {
        int row = w * 32 + rr;
        int node = node0 + row;
        if (node >= N) continue;
        bf16x2 o;
        o.x = (bf16)acc[row * 128 + lane];
        o.y = (bf16)acc[row * 128 + 64 + lane];
        ((bf16x2*)dst)[(size_t)node * 64 + lane] = o;
    }
    if (t < 128 && node0 + t < N) deg[node0 + t] = degs[t];
}

// Fused GEMM + bias + exact GELU.
// Block: 256 thr = 4 waves (2x2), tile 128 nodes x 128 feats, K=384 in 12 chunks
// of 32. Each wave: 4x4 grid of 16x16x32 bf16 MFMAs.
// A frag lane: m=lane&15, k=(lane>>4)*8+j; B frag same with n; C/D: col=lane&15,
// row=(lane>>4)*4+r. (k-permutation consistent between A and B staging.)
__global__ __launch_bounds__(256) void k_gemm(
    const bf16* __restrict__ h, const bf16* __restrict__ AH, const bf16* __restrict__ ATH,
    const float* __restrict__ Ws_w, const float* __restrict__ W_w, const float* __restrict__ Wt_w,
    const float* __restrict__ Ws_b, const float* __restrict__ W_b, const float* __restrict__ Wt_b,
    const int* __restrict__ deg_out, const int* __restrict__ deg_in,
    float* __restrict__ out, int N) {
    __shared__ __align__(16) bf16 Ash[128 * 32];
    __shared__ __align__(16) bf16 Bsh[128 * 32];
    int t = threadIdx.x;
    int lane = t & 63;
    int w = t >> 6;
    int wm = (w >> 1) * 64, wn = (w & 1) * 64;
    int m0 = blockIdx.x * 128;

    f32x4 acc[4][4];
#pragma unroll
    for (int i = 0; i < 4; ++i)
#pragma unroll
        for (int j = 0; j < 4; ++j)
            acc[i][j] = (f32x4){0.f, 0.f, 0.f, 0.f};

    for (int kc = 0; kc < 12; ++kc) {
        const bf16*  X  = (kc < 4) ? h    : (kc < 8) ? AH  : ATH;
        const float* Wm = (kc < 4) ? Ws_w : (kc < 8) ? W_w : Wt_w;
        int c0 = (kc & 3) * 32;
#pragma unroll
        for (int r = 0; r < 2; ++r) {
            int v = r * 256 + t;
            int row = v >> 2, seg = v & 3;
            int xr = m0 + row; if (xr >= N) xr = N - 1;  // clamp, stores guarded
            *(bf16x8*)&Ash[row * 32 + seg * 8] =
                *(const bf16x8*)&X[(size_t)xr * D + c0 + seg * 8];
        }
#pragma unroll
        for (int r = 0; r < 4; ++r) {
            int v = r * 256 + t;
            int row = v >> 3, seg = v & 7;
            f32x4 f = *(const f32x4*)&Wm[row * D + c0 + seg * 4];
            bf16x4 o;
            o.x = (bf16)f.x; o.y = (bf16)f.y; o.z = (bf16)f.z; o.w = (bf16)f.w;
            *(bf16x4*)&Bsh[row * 32 + seg * 4] = o;
        }
        __syncthreads();
        int kg = lane >> 4, lr = lane & 15;
        bf16x8 a[4], b[4];
#pragma unroll
        for (int i = 0; i < 4; ++i) {
            a[i] = *(const bf16x8*)&Ash[(wm + i * 16 + lr) * 32 + kg * 8];
            b[i] = *(const bf16x8*)&Bsh[(wn + i * 16 + lr) * 32 + kg * 8];
        }
#pragma unroll
        for (int i = 0; i < 4; ++i)
#pragma unroll
            for (int j = 0; j < 4; ++j)
                acc[i][j] = __builtin_amdgcn_mfma_f32_16x16x32_bf16(
                    a[i], b[j], acc[i][j], 0, 0, 0);
        __syncthreads();
    }

    int lr = lane & 15, lq = lane >> 4;
#pragma unroll
    for (int i = 0; i < 4; ++i) {
#pragma unroll
        for (int r = 0; r < 4; ++r) {
            int node = m0 + wm + i * 16 + lq * 4 + r;
            if (node >= N) continue;
            float fdr = (float)deg_out[node], fdc = (float)deg_in[node];
#pragma unroll
            for (int j = 0; j < 4; ++j) {
                int f = wn + j * 16 + lr;
                float val = acc[i][j][r] + Ws_b[f] + fdr * W_b[f] + fdc * Wt_b[f];
                float g = 0.5f * val * (1.0f + erff(val * 0.70710678118654752f));
                out[(size_t)node * D + f] = g;
            }
        }
    }
}

extern "C" void kernel_launch(void* const* d_in, const int* in_sizes, int n_in,
                              void* d_out, int out_size, void* d_ws, size_t ws_size,
                              hipStream_t stream) {
    const float* h    = (const float*)d_in[0];
    const float* W_w  = (const float*)d_in[1];
    const float* W_b  = (const float*)d_in[2];
    const float* Wt_w = (const float*)d_in[3];
    const float* Wt_b = (const float*)d_in[4];
    const float* Ws_w = (const float*)d_in[5];
    const float* Ws_b = (const float*)d_in[6];
    const int*   rows = (const int*)d_in[7];
    const int*   cols = (const int*)d_in[8];
    float* out = (float*)d_out;

    const int N = in_sizes[0] / D;        // 100000
    const int E = in_sizes[7];            // 1600000
    const int B = (N + 127) >> 7;         // 782 buckets

    char* ws = (char*)d_ws;
    size_t off = 0;
    auto take = [&](size_t bytes) -> char* {
        char* p = ws + off;
        off += (bytes + 511) & ~(size_t)511;
        return p;
    };
    bf16* h_bf    = (bf16*)take((size_t)N * D * sizeof(bf16));     // 25.6 MB
    bf16* AH      = (bf16*)take((size_t)N * D * sizeof(bf16));     // 25.6 MB
    bf16* ATH     = (bf16*)take((size_t)N * D * sizeof(bf16));     // 25.6 MB
    int*  cnt     = (int*)take((size_t)2 * B * sizeof(int));       // cnt_f | cnt_r
    int*  deg_out = (int*)take((size_t)N * sizeof(int));
    int*  deg_in  = (int*)take((size_t)N * sizeof(int));
    u32*  buf_f   = (u32*)take((size_t)B * BKT_CAP * sizeof(u32)); // 7.6 MB
    u32*  buf_r   = (u32*)take((size_t)B * BKT_CAP * sizeof(u32)); // 7.6 MB
    int*  cnt_f = cnt, *cnt_r = cnt + B;

    hipMemsetAsync(cnt, 0, (size_t)2 * B * sizeof(int), stream);

    int n4 = N * D / 4;
    k_cast<<<(n4 + 255) / 256, 256, 0, stream>>>(h, h_bf, n4);

    k_bin<<<(E + 255) / 256, 256, 0, stream>>>(rows, cols, cnt_f, cnt_r,
                                               buf_f, buf_r, E);
    dim3 gagg(B, 2);
    k_agg<<<gagg, 256, 0, stream>>>(h_bf, cnt_f, cnt_r, buf_f, buf_r,
                                    AH, ATH, deg_out, deg_in, N);
    k_gemm<<<B, 256, 0, stream>>>(h_bf, AH, ATH,
                                  Ws_w, W_w, Wt_w,
                                  Ws_b, W_b, Wt_b,
                                  deg_out, deg_in, out, N);
}

// Round 4
// 380.186 us; speedup vs baseline: 7.7971x; 7.7971x over previous
//
#include <hip/hip_runtime.h>

// BiMPNN layer, MI355X. f32 I/O, bf16 MFMA internally.
//   agg  = A  @ (h@W^T  + b)  ==  (A @ h) @ W^T  + deg_out * b   (linearity)
//   aggt = A^T@ (h@Wt^T + bt) ==  (A^T@ h) @ Wt^T + deg_in  * bt
// R4: (a) k_bin uses block-aggregated reservation (LDS hist -> 1 global
// atomic-return per (block,bucket) -> LDS-rank scatter): 3.2M -> ~1.2M global
// atomics (R3 showed k_bin ~535us dominated by atomic-with-return cost).
// (b) k_sort: per-bucket LDS counting sort -> exact per-node CSR (off/deg).
// (c) k_agg: wave-per-node register accumulation, 200k waves (R3's 64KB-LDS
// accumulator was latency-bound at 20% occupancy / 2.2% VALUBusy).

typedef __bf16 bf16;
typedef __bf16 bf16x2 __attribute__((ext_vector_type(2)));
typedef __bf16 bf16x4 __attribute__((ext_vector_type(4)));
typedef __bf16 bf16x8 __attribute__((ext_vector_type(8)));
typedef float  f32x4  __attribute__((ext_vector_type(4)));
typedef unsigned int u32;

#define D 128
#define BKT_CAP 2432   // mean edges/bucket = 1.6M/782 = 2046, +8.5 sigma
#define BIN_CHUNK 2048 // edges per k_bin block (8 per thread)

__global__ void k_cast(const float* __restrict__ src, bf16* __restrict__ dst, int n4) {
    int i = blockIdx.x * 256 + threadIdx.x;
    if (i < n4) {
        f32x4 v = *(const f32x4*)&src[i * 4];
        bf16x4 o;
        o.x = (bf16)v.x; o.y = (bf16)v.y; o.z = (bf16)v.z; o.w = (bf16)v.w;
        *(bf16x4*)&dst[i * 4] = o;
    }
}

// Block-aggregated binning: per-block LDS histogram over buckets, one global
// atomicAdd per (block,bucket) to reserve a contiguous range, then LDS-cursor
// scatter of packed words ((node&127)<<17 | src) to exact positions.
__global__ __launch_bounds__(256) void k_bin(
    const int* __restrict__ rows, const int* __restrict__ cols,
    int* __restrict__ gcnt_f, int* __restrict__ gcnt_r,
    u32* __restrict__ buf_f, u32* __restrict__ buf_r, int E, int B) {
    __shared__ int hf[1024], hr[1024];
    int t = threadIdx.x;
    int base = blockIdx.x * BIN_CHUNK;
    for (int b = t; b < B; b += 256) { hf[b] = 0; hr[b] = 0; }
    __syncthreads();
    int r[8], c[8];
#pragma unroll
    for (int i = 0; i < 8; ++i) {
        int e = base + i * 256 + t;
        if (e < E) {
            r[i] = rows[e]; c[i] = cols[e];
            atomicAdd(&hf[r[i] >> 7], 1);
            atomicAdd(&hr[c[i] >> 7], 1);
        }
    }
    __syncthreads();
    for (int b = t; b < B; b += 256) {
        int v = hf[b]; if (v) hf[b] = atomicAdd(&gcnt_f[b], v);  // LDS now = global base
        int w = hr[b]; if (w) hr[b] = atomicAdd(&gcnt_r[b], w);
    }
    __syncthreads();
#pragma unroll
    for (int i = 0; i < 8; ++i) {
        int e = base + i * 256 + t;
        if (e < E) {
            int p = atomicAdd(&hf[r[i] >> 7], 1);   // base + rank
            if (p < BKT_CAP)
                buf_f[(size_t)(r[i] >> 7) * BKT_CAP + p] =
                    ((u32)(r[i] & 127) << 17) | (u32)c[i];
            int q = atomicAdd(&hr[c[i] >> 7], 1);
            if (q < BKT_CAP)
                buf_r[(size_t)(c[i] >> 7) * BKT_CAP + q] =
                    ((u32)(c[i] & 127) << 17) | (u32)r[i];
        }
    }
}

// Per-bucket LDS counting sort by local node (7 bits). Rewrites buf in place
// with src-only words grouped by node; emits absolute off[] and deg[] per node.
__global__ __launch_bounds__(256) void k_sort(
    const int* __restrict__ cnt_f, const int* __restrict__ cnt_r,
    u32* __restrict__ buf_f, u32* __restrict__ buf_r,
    int* __restrict__ off_f, int* __restrict__ off_r,
    int* __restrict__ deg_f, int* __restrict__ deg_r, int N) {
    __shared__ u32 words[BKT_CAP];
    __shared__ u32 sorted[BKT_CAP];
    __shared__ int hist[128], scn[128];
    int t = threadIdx.x, bkt = blockIdx.x;
    const int* cp; u32* buf; int* off; int* deg;
    if (blockIdx.y == 0) { cp = cnt_f; buf = buf_f + (size_t)bkt * BKT_CAP; off = off_f; deg = deg_f; }
    else                 { cp = cnt_r; buf = buf_r + (size_t)bkt * BKT_CAP; off = off_r; deg = deg_r; }
    int cnt = cp[bkt]; if (cnt > BKT_CAP) cnt = BKT_CAP;
    if (t < 128) hist[t] = 0;
    __syncthreads();
    for (int i = t; i < cnt; i += 256) {
        u32 w = buf[i]; words[i] = w;
        atomicAdd(&hist[w >> 17], 1);
    }
    __syncthreads();
    if (t < 128) scn[t] = hist[t];
    __syncthreads();
    for (int o = 1; o < 128; o <<= 1) {          // Hillis-Steele inclusive scan
        int v = (t < 128 && t >= o) ? scn[t - o] : 0;
        __syncthreads();
        if (t < 128) scn[t] += v;
        __syncthreads();
    }
    int node0 = bkt * 128;
    if (t < 128) {
        int start = scn[t] - hist[t];
        hist[t] = start;                          // becomes cursor
        int node = node0 + t;
        if (node < N) { off[node] = bkt * BKT_CAP + start; deg[node] = scn[t] - start; }
    }
    __syncthreads();
    for (int i = t; i < cnt; i += 256) {
        u32 w = words[i];
        int p = atomicAdd(&hist[w >> 17], 1);
        sorted[p] = w & 0x1FFFF;
    }
    __syncthreads();
    for (int i = t; i < cnt; i += 256) buf[i] = sorted[i];
}

// One wave per (node, direction): lane holds 2 feature dims (bf16x2 = 4B/lane,
// 256B/edge coalesced gather), 4 independent f32 accumulator pairs, bf16 store.
__global__ void k_agg(const bf16* __restrict__ h,
                      const int* __restrict__ off_f, const int* __restrict__ deg_f,
                      const u32* __restrict__ buf_f,
                      const int* __restrict__ off_r, const int* __restrict__ deg_r,
                      const u32* __restrict__ buf_r,
                      bf16* __restrict__ AH, bf16* __restrict__ ATH, int N) {
    int wave = threadIdx.x >> 6, lane = threadIdx.x & 63;
    int node = blockIdx.x * 4 + wave;
    if (node >= N) return;
    const int* off; const int* deg; const u32* idx; bf16* dst;
    if (blockIdx.y == 0) { off = off_f; deg = deg_f; idx = buf_f; dst = AH; }
    else                 { off = off_r; deg = deg_r; idx = buf_r; dst = ATH; }
    const bf16x2* h2 = (const bf16x2*)h;
    int p = off[node], end = p + deg[node];
    float ax0 = 0.f, ay0 = 0.f, ax1 = 0.f, ay1 = 0.f;
    float ax2 = 0.f, ay2 = 0.f, ax3 = 0.f, ay3 = 0.f;
    for (; p + 3 < end; p += 4) {
        u32 j0 = idx[p], j1 = idx[p + 1], j2 = idx[p + 2], j3 = idx[p + 3];
        bf16x2 v0 = h2[(size_t)j0 * 64 + lane];
        bf16x2 v1 = h2[(size_t)j1 * 64 + lane];
        bf16x2 v2 = h2[(size_t)j2 * 64 + lane];
        bf16x2 v3 = h2[(size_t)j3 * 64 + lane];
        ax0 += (float)v0.x; ay0 += (float)v0.y;
        ax1 += (float)v1.x; ay1 += (float)v1.y;
        ax2 += (float)v2.x; ay2 += (float)v2.y;
        ax3 += (float)v3.x; ay3 += (float)v3.y;
    }
    for (; p < end; ++p) {
        u32 j0 = idx[p];
        bf16x2 v0 = h2[(size_t)j0 * 64 + lane];
        ax0 += (float)v0.x; ay0 += (float)v0.y;
    }
    bf16x2 o;
    o.x = (bf16)((ax0 + ax1) + (ax2 + ax3));
    o.y = (bf16)((ay0 + ay1) + (ay2 + ay3));
    ((bf16x2*)dst)[(size_t)node * 64 + lane] = o;
}

// Fused GEMM + bias + exact GELU.
// Block: 256 thr = 4 waves (2x2), tile 128 nodes x 128 feats, K=384 in 12 chunks
// of 32. Each wave: 4x4 grid of 16x16x32 bf16 MFMAs.
// A frag lane: m=lane&15, k=(lane>>4)*8+j; B frag same with n; C/D: col=lane&15,
// row=(lane>>4)*4+r. (k-permutation consistent between A and B staging.)
__global__ __launch_bounds__(256) void k_gemm(
    const bf16* __restrict__ h, const bf16* __restrict__ AH, const bf16* __restrict__ ATH,
    const float* __restrict__ Ws_w, const float* __restrict__ W_w, const float* __restrict__ Wt_w,
    const float* __restrict__ Ws_b, const float* __restrict__ W_b, const float* __restrict__ Wt_b,
    const int* __restrict__ deg_out, const int* __restrict__ deg_in,
    float* __restrict__ out, int N) {
    __shared__ __align__(16) bf16 Ash[128 * 32];
    __shared__ __align__(16) bf16 Bsh[128 * 32];
    int t = threadIdx.x;
    int lane = t & 63;
    int w = t >> 6;
    int wm = (w >> 1) * 64, wn = (w & 1) * 64;
    int m0 = blockIdx.x * 128;

    f32x4 acc[4][4];
#pragma unroll
    for (int i = 0; i < 4; ++i)
#pragma unroll
        for (int j = 0; j < 4; ++j)
            acc[i][j] = (f32x4){0.f, 0.f, 0.f, 0.f};

    for (int kc = 0; kc < 12; ++kc) {
        const bf16*  X  = (kc < 4) ? h    : (kc < 8) ? AH  : ATH;
        const float* Wm = (kc < 4) ? Ws_w : (kc < 8) ? W_w : Wt_w;
        int c0 = (kc & 3) * 32;
#pragma unroll
        for (int r = 0; r < 2; ++r) {
            int v = r * 256 + t;
            int row = v >> 2, seg = v & 3;
            int xr = m0 + row; if (xr >= N) xr = N - 1;  // clamp, stores guarded
            *(bf16x8*)&Ash[row * 32 + seg * 8] =
                *(const bf16x8*)&X[(size_t)xr * D + c0 + seg * 8];
        }
#pragma unroll
        for (int r = 0; r < 4; ++r) {
            int v = r * 256 + t;
            int row = v >> 3, seg = v & 7;
            f32x4 f = *(const f32x4*)&Wm[row * D + c0 + seg * 4];
            bf16x4 o;
            o.x = (bf16)f.x; o.y = (bf16)f.y; o.z = (bf16)f.z; o.w = (bf16)f.w;
            *(bf16x4*)&Bsh[row * 32 + seg * 4] = o;
        }
        __syncthreads();
        int kg = lane >> 4, lr = lane & 15;
        bf16x8 a[4], b[4];
#pragma unroll
        for (int i = 0; i < 4; ++i) {
            a[i] = *(const bf16x8*)&Ash[(wm + i * 16 + lr) * 32 + kg * 8];
            b[i] = *(const bf16x8*)&Bsh[(wn + i * 16 + lr) * 32 + kg * 8];
        }
#pragma unroll
        for (int i = 0; i < 4; ++i)
#pragma unroll
            for (int j = 0; j < 4; ++j)
                acc[i][j] = __builtin_amdgcn_mfma_f32_16x16x32_bf16(
                    a[i], b[j], acc[i][j], 0, 0, 0);
        __syncthreads();
    }

    int lr = lane & 15, lq = lane >> 4;
#pragma unroll
    for (int i = 0; i < 4; ++i) {
#pragma unroll
        for (int r = 0; r < 4; ++r) {
            int node = m0 + wm + i * 16 + lq * 4 + r;
            if (node >= N) continue;
            float fdr = (float)deg_out[node], fdc = (float)deg_in[node];
#pragma unroll
            for (int j = 0; j < 4; ++j) {
                int f = wn + j * 16 + lr;
                float val = acc[i][j][r] + Ws_b[f] + fdr * W_b[f] + fdc * Wt_b[f];
                float g = 0.5f * val * (1.0f + erff(val * 0.70710678118654752f));
                out[(size_t)node * D + f] = g;
            }
        }
    }
}

extern "C" void kernel_launch(void* const* d_in, const int* in_sizes, int n_in,
                              void* d_out, int out_size, void* d_ws, size_t ws_size,
                              hipStream_t stream) {
    const float* h    = (const float*)d_in[0];
    const float* W_w  = (const float*)d_in[1];
    const float* W_b  = (const float*)d_in[2];
    const float* Wt_w = (const float*)d_in[3];
    const float* Wt_b = (const float*)d_in[4];
    const float* Ws_w = (const float*)d_in[5];
    const float* Ws_b = (const float*)d_in[6];
    const int*   rows = (const int*)d_in[7];
    const int*   cols = (const int*)d_in[8];
    float* out = (float*)d_out;

    const int N = in_sizes[0] / D;        // 100000
    const int E = in_sizes[7];            // 1600000
    const int B = (N + 127) >> 7;         // 782 buckets

    char* ws = (char*)d_ws;
    size_t off = 0;
    auto take = [&](size_t bytes) -> char* {
        char* p = ws + off;
        off += (bytes + 511) & ~(size_t)511;
        return p;
    };
    bf16* h_bf    = (bf16*)take((size_t)N * D * sizeof(bf16));     // 25.6 MB
    bf16* AH      = (bf16*)take((size_t)N * D * sizeof(bf16));     // 25.6 MB
    bf16* ATH     = (bf16*)take((size_t)N * D * sizeof(bf16));     // 25.6 MB
    int*  gcnt    = (int*)take((size_t)2 * B * sizeof(int));       // gcnt_f | gcnt_r
    int*  off_f   = (int*)take((size_t)N * sizeof(int));
    int*  off_r   = (int*)take((size_t)N * sizeof(int));
    int*  deg_f   = (int*)take((size_t)N * sizeof(int));
    int*  deg_r   = (int*)take((size_t)N * sizeof(int));
    u32*  buf_f   = (u32*)take((size_t)B * BKT_CAP * sizeof(u32)); // 7.6 MB
    u32*  buf_r   = (u32*)take((size_t)B * BKT_CAP * sizeof(u32)); // 7.6 MB
    int*  gcnt_f = gcnt, *gcnt_r = gcnt + B;

    hipMemsetAsync(gcnt, 0, (size_t)2 * B * sizeof(int), stream);

    int n4 = N * D / 4;
    k_cast<<<(n4 + 255) / 256, 256, 0, stream>>>(h, h_bf, n4);

    k_bin<<<(E + BIN_CHUNK - 1) / BIN_CHUNK, 256, 0, stream>>>(
        rows, cols, gcnt_f, gcnt_r, buf_f, buf_r, E, B);
    dim3 gsort(B, 2);
    k_sort<<<gsort, 256, 0, stream>>>(gcnt_f, gcnt_r, buf_f, buf_r,
                                      off_f, off_r, deg_f, deg_r, N);
    dim3 gagg((N + 3) / 4, 2);
    k_agg<<<gagg, 256, 0, stream>>>(h_bf, off_f, deg_f, buf_f,
                                    off_r, deg_r, buf_r, AH, ATH, N);
    k_gemm<<<B, 256, 0, stream>>>(h_bf, AH, ATH,
                                  Ws_w, W_w, Wt_w,
                                  Ws_b, W_b, Wt_b,
                                  deg_f, deg_r, out, N);
}

// Round 5
// 347.839 us; speedup vs baseline: 8.5222x; 1.0930x over previous
//
#include <hip/hip_runtime.h>

// BiMPNN layer, MI355X. f32 I/O, bf16 MFMA internally.
//   agg  = A  @ (h@W^T  + b)  ==  (A @ h) @ W^T  + deg_out * b   (linearity)
//   aggt = A^T@ (h@Wt^T + bt) ==  (A^T@ h) @ Wt^T + deg_in  * bt
// R5: (a) k_bin: 12544-edge blocks, in-LDS counting sort by bucket, ONE global
// atomic-return per (block,bucket) (~200k vs 1.2M), line-sized contiguous
// copy-out runs (avg 16 words = 64B). (b) k_agg: split-wave 8B/lane gathers
// (2 edges per load inst), bit-op bf16->f32, shfl cross-half reduce; node lists
// padded to even with zero-row sentinel. (c) k_sort emits padded layout.

typedef __bf16 bf16;
typedef __bf16 bf16x4 __attribute__((ext_vector_type(4)));
typedef __bf16 bf16x8 __attribute__((ext_vector_type(8)));
typedef float  f32x4  __attribute__((ext_vector_type(4)));
typedef unsigned int u32;
typedef u32 u32x2 __attribute__((ext_vector_type(2)));

#define D 128
#define CAPC 2432      // max real edges/bucket (mean 2046, +8.5 sigma)
#define SLAB 2560      // slab stride: CAPC + 128 pad slots
#define BIN_CHUNK 12544  // 49 * 256 edges per k_bin block

__global__ void k_cast(const float* __restrict__ src, bf16* __restrict__ dst, int n4) {
    int i = blockIdx.x * 256 + threadIdx.x;
    if (i < n4) {
        f32x4 v = *(const f32x4*)&src[i * 4];
        bf16x4 o;
        o.x = (bf16)v.x; o.y = (bf16)v.y; o.z = (bf16)v.z; o.w = (bf16)v.w;
        *(bf16x4*)&dst[i * 4] = o;
    }
}

// In-LDS counting sort by bucket, then line-grouped copy-out to global slabs.
// blockIdx.y = direction. packed word: (node&127)<<17 | src.
__global__ __launch_bounds__(256) void k_bin(
    const int* __restrict__ rows, const int* __restrict__ cols,
    int* __restrict__ gcnt_f, int* __restrict__ gcnt_r,
    u32* __restrict__ buf_f, u32* __restrict__ buf_r, int E, int B) {
    __shared__ int hist[1024];    // counts -> cursors
    __shared__ int lbase[1024];   // local exclusive base
    __shared__ int gbase[1024];   // global reserved base
    __shared__ int tsum[256];
    __shared__ u32 sorted[BIN_CHUNK];
    int t = threadIdx.x;
    int dir = blockIdx.y;
    const int* key = dir ? cols : rows;
    const int* pay = dir ? rows : cols;
    int* gcnt = dir ? gcnt_r : gcnt_f;
    u32* buf  = dir ? buf_r : buf_f;
    int base = blockIdx.x * BIN_CHUNK;

    for (int b = t; b < 1024; b += 256) hist[b] = 0;
    __syncthreads();
    for (int i = 0; i < BIN_CHUNK / 256; ++i) {
        int e = base + i * 256 + t;
        if (e < E) atomicAdd(&hist[key[e] >> 7], 1);
    }
    __syncthreads();
    // two-level exclusive scan over 1024 buckets (4 consecutive per thread)
    int s0 = hist[t * 4], s1 = hist[t * 4 + 1], s2 = hist[t * 4 + 2], s3 = hist[t * 4 + 3];
    tsum[t] = s0 + s1 + s2 + s3;
    __syncthreads();
    for (int o = 1; o < 256; o <<= 1) {
        int v = (t >= o) ? tsum[t - o] : 0;
        __syncthreads();
        tsum[t] += v;
        __syncthreads();
    }
    int run = (t > 0) ? tsum[t - 1] : 0;
    lbase[t * 4]     = run;
    lbase[t * 4 + 1] = run + s0;
    lbase[t * 4 + 2] = run + s0 + s1;
    lbase[t * 4 + 3] = run + s0 + s1 + s2;
    __syncthreads();
    int total = tsum[255];
    // reserve global ranges; convert hist to local cursor
    for (int b = t; b < 1024; b += 256) {
        int nxt = (b < 1023) ? lbase[b + 1] : total;
        int c = nxt - lbase[b];
        gbase[b] = (c && b < B) ? atomicAdd(&gcnt[b], c) : 0;
        hist[b] = lbase[b];
    }
    __syncthreads();
    // rank-scatter into LDS (sorted by bucket)
    for (int i = 0; i < BIN_CHUNK / 256; ++i) {
        int e = base + i * 256 + t;
        if (e < E) {
            int k = key[e], p = pay[e];
            int pos = atomicAdd(&hist[k >> 7], 1);
            sorted[pos] = ((u32)(k & 127) << 17) | (u32)p;
        }
    }
    __syncthreads();
    // contiguous copy-out per bucket (avg run = 16 words = one 64B line)
    for (int b = t; b < B; b += 256) {
        int lb = lbase[b];
        int nxt = (b < 1023) ? lbase[b + 1] : total;
        int c = nxt - lb;
        if (!c) continue;
        int gb = gbase[b];
        u32* dst = buf + (size_t)b * SLAB;
        for (int i = 0; i < c; ++i) {
            int gp = gb + i;
            if (gp < CAPC) dst[gp] = sorted[lb + i];
        }
    }
}

// Per-bucket LDS counting sort by local node (7 bits). Rewrites slab with
// src-only words grouped by node, each node's run padded to EVEN length with
// PADV (zero row). Emits absolute off[] (padded layout) and true deg[].
__global__ __launch_bounds__(256) void k_sort(
    const int* __restrict__ cnt_f, const int* __restrict__ cnt_r,
    u32* __restrict__ buf_f, u32* __restrict__ buf_r,
    int* __restrict__ off_f, int* __restrict__ off_r,
    int* __restrict__ deg_f, int* __restrict__ deg_r, int N, u32 PADV) {
    __shared__ u32 words[CAPC];
    __shared__ u32 sorted[SLAB];
    __shared__ int hist[128], pscn[128], cur[128];
    int t = threadIdx.x, bkt = blockIdx.x;
    const int* cp; u32* buf; int* off; int* deg;
    if (blockIdx.y == 0) { cp = cnt_f; buf = buf_f + (size_t)bkt * SLAB; off = off_f; deg = deg_f; }
    else                 { cp = cnt_r; buf = buf_r + (size_t)bkt * SLAB; off = off_r; deg = deg_r; }
    int cnt = cp[bkt]; if (cnt > CAPC) cnt = CAPC;
    if (t < 128) hist[t] = 0;
    __syncthreads();
    for (int i = t; i < cnt; i += 256) {
        u32 w = buf[i]; words[i] = w;
        atomicAdd(&hist[w >> 17], 1);
    }
    __syncthreads();
    int pd = 0;
    if (t < 128) { pd = (hist[t] + 1) & ~1; pscn[t] = pd; }
    __syncthreads();
    for (int o = 1; o < 128; o <<= 1) {          // inclusive scan of padded degs
        int v = (t < 128 && t >= o) ? pscn[t - o] : 0;
        __syncthreads();
        if (t < 128) pscn[t] += v;
        __syncthreads();
    }
    int ptot = pscn[127];
    int node0 = bkt * 128;
    if (t < 128) {
        int pstart = pscn[t] - pd;
        cur[t] = pstart;
        int node = node0 + t;
        if (node < N) { off[node] = bkt * SLAB + pstart; deg[node] = hist[t]; }
    }
    __syncthreads();
    for (int i = t; i < ptot; i += 256) sorted[i] = PADV;
    __syncthreads();
    for (int i = t; i < cnt; i += 256) {
        u32 w = words[i];
        int p = atomicAdd(&cur[w >> 17], 1);
        sorted[p] = w & 0x1FFFF;
    }
    __syncthreads();
    for (int i = t; i < ptot; i += 256) buf[i] = sorted[i];
}

__device__ __forceinline__ float blo(u32 w) { return __uint_as_float(w << 16); }
__device__ __forceinline__ float bhi(u32 w) { return __uint_as_float(w & 0xffff0000u); }

// One wave per (node, direction). Split wave: lanes 0-31 even edges, 32-63 odd
// edges; 8B/lane (4 feats) -> one dwordx2 gather covers 2 edges per wave-inst.
// Edge lists pre-padded to even length with PADV -> zero row, no tail branch.
__global__ void k_agg(const bf16* __restrict__ h,
                      const int* __restrict__ off_f, const int* __restrict__ deg_f,
                      const u32* __restrict__ buf_f,
                      const int* __restrict__ off_r, const int* __restrict__ deg_r,
                      const u32* __restrict__ buf_r,
                      bf16* __restrict__ AH, bf16* __restrict__ ATH, int N) {
    int wave = threadIdx.x >> 6, lane = threadIdx.x & 63;
    int node = blockIdx.x * 4 + wave;
    if (node >= N) return;
    const int* off; const int* deg; const u32* idx; bf16* dst;
    if (blockIdx.y == 0) { off = off_f; deg = deg_f; idx = buf_f; dst = AH; }
    else                 { off = off_r; deg = deg_r; idx = buf_r; dst = ATH; }
    int p = off[node];
    int pend = p + ((deg[node] + 1) & ~1);
    int half = lane >> 5, col = lane & 31;
    const u32* h32 = (const u32*)h;           // one row = 64 dwords
    float a0 = 0.f, a1 = 0.f, a2 = 0.f, a3 = 0.f;
    for (; p + 7 < pend; p += 8) {
        u32 j[4];
#pragma unroll
        for (int u = 0; u < 4; ++u) j[u] = idx[p + 2 * u + half];
#pragma unroll
        for (int u = 0; u < 4; ++u) {
            u32x2 w = *(const u32x2*)&h32[(size_t)j[u] * 64 + col * 2];
            a0 += blo(w.x); a1 += bhi(w.x);
            a2 += blo(w.y); a3 += bhi(w.y);
        }
    }
    for (; p + 1 < pend; p += 2) {
        u32 j = idx[p + half];
        u32x2 w = *(const u32x2*)&h32[(size_t)j * 64 + col * 2];
        a0 += blo(w.x); a1 += bhi(w.x);
        a2 += blo(w.y); a3 += bhi(w.y);
    }
    a0 += __shfl_down(a0, 32);
    a1 += __shfl_down(a1, 32);
    a2 += __shfl_down(a2, 32);
    a3 += __shfl_down(a3, 32);
    if (half == 0) {
        bf16x4 o;
        o.x = (bf16)a0; o.y = (bf16)a1; o.z = (bf16)a2; o.w = (bf16)a3;
        *(bf16x4*)&dst[(size_t)node * D + col * 4] = o;
    }
}

// Fused GEMM + bias + exact GELU (unchanged from R4).
__global__ __launch_bounds__(256) void k_gemm(
    const bf16* __restrict__ h, const bf16* __restrict__ AH, const bf16* __restrict__ ATH,
    const float* __restrict__ Ws_w, const float* __restrict__ W_w, const float* __restrict__ Wt_w,
    const float* __restrict__ Ws_b, const float* __restrict__ W_b, const float* __restrict__ Wt_b,
    const int* __restrict__ deg_out, const int* __restrict__ deg_in,
    float* __restrict__ out, int N) {
    __shared__ __align__(16) bf16 Ash[128 * 32];
    __shared__ __align__(16) bf16 Bsh[128 * 32];
    int t = threadIdx.x;
    int lane = t & 63;
    int w = t >> 6;
    int wm = (w >> 1) * 64, wn = (w & 1) * 64;
    int m0 = blockIdx.x * 128;

    f32x4 acc[4][4];
#pragma unroll
    for (int i = 0; i < 4; ++i)
#pragma unroll
        for (int j = 0; j < 4; ++j)
            acc[i][j] = (f32x4){0.f, 0.f, 0.f, 0.f};

    for (int kc = 0; kc < 12; ++kc) {
        const bf16*  X  = (kc < 4) ? h    : (kc < 8) ? AH  : ATH;
        const float* Wm = (kc < 4) ? Ws_w : (kc < 8) ? W_w : Wt_w;
        int c0 = (kc & 3) * 32;
#pragma unroll
        for (int r = 0; r < 2; ++r) {
            int v = r * 256 + t;
            int row = v >> 2, seg = v & 3;
            int xr = m0 + row; if (xr >= N) xr = N - 1;  // clamp, stores guarded
            *(bf16x8*)&Ash[row * 32 + seg * 8] =
                *(const bf16x8*)&X[(size_t)xr * D + c0 + seg * 8];
        }
#pragma unroll
        for (int r = 0; r < 4; ++r) {
            int v = r * 256 + t;
            int row = v >> 3, seg = v & 7;
            f32x4 f = *(const f32x4*)&Wm[row * D + c0 + seg * 4];
            bf16x4 o;
            o.x = (bf16)f.x; o.y = (bf16)f.y; o.z = (bf16)f.z; o.w = (bf16)f.w;
            *(bf16x4*)&Bsh[row * 32 + seg * 4] = o;
        }
        __syncthreads();
        int kg = lane >> 4, lr = lane & 15;
        bf16x8 a[4], b[4];
#pragma unroll
        for (int i = 0; i < 4; ++i) {
            a[i] = *(const bf16x8*)&Ash[(wm + i * 16 + lr) * 32 + kg * 8];
            b[i] = *(const bf16x8*)&Bsh[(wn + i * 16 + lr) * 32 + kg * 8];
        }
#pragma unroll
        for (int i = 0; i < 4; ++i)
#pragma unroll
            for (int j = 0; j < 4; ++j)
                acc[i][j] = __builtin_amdgcn_mfma_f32_16x16x32_bf16(
                    a[i], b[j], acc[i][j], 0, 0, 0);
        __syncthreads();
    }

    int lr = lane & 15, lq = lane >> 4;
#pragma unroll
    for (int i = 0; i < 4; ++i) {
#pragma unroll
        for (int r = 0; r < 4; ++r) {
            int node = m0 + wm + i * 16 + lq * 4 + r;
            if (node >= N) continue;
            float fdr = (float)deg_out[node], fdc = (float)deg_in[node];
#pragma unroll
            for (int j = 0; j < 4; ++j) {
                int f = wn + j * 16 + lr;
                float val = acc[i][j][r] + Ws_b[f] + fdr * W_b[f] + fdc * Wt_b[f];
                float g = 0.5f * val * (1.0f + erff(val * 0.70710678118654752f));
                out[(size_t)node * D + f] = g;
            }
        }
    }
}

extern "C" void kernel_launch(void* const* d_in, const int* in_sizes, int n_in,
                              void* d_out, int out_size, void* d_ws, size_t ws_size,
                              hipStream_t stream) {
    const float* h    = (const float*)d_in[0];
    const float* W_w  = (const float*)d_in[1];
    const float* W_b  = (const float*)d_in[2];
    const float* Wt_w = (const float*)d_in[3];
    const float* Wt_b = (const float*)d_in[4];
    const float* Ws_w = (const float*)d_in[5];
    const float* Ws_b = (const float*)d_in[6];
    const int*   rows = (const int*)d_in[7];
    const int*   cols = (const int*)d_in[8];
    float* out = (float*)d_out;

    const int N = in_sizes[0] / D;        // 100000
    const int E = in_sizes[7];            // 1600000
    const int B = (N + 127) >> 7;         // 782 buckets

    char* ws = (char*)d_ws;
    size_t off = 0;
    auto take = [&](size_t bytes) -> char* {
        char* p = ws + off;
        off += (bytes + 511) & ~(size_t)511;
        return p;
    };
    bf16* h_bf    = (bf16*)take((size_t)(N + 1) * D * sizeof(bf16)); // +1 zero row
    bf16* AH      = (bf16*)take((size_t)N * D * sizeof(bf16));
    bf16* ATH     = (bf16*)take((size_t)N * D * sizeof(bf16));
    int*  gcnt    = (int*)take((size_t)2 * B * sizeof(int));
    int*  off_f   = (int*)take((size_t)N * sizeof(int));
    int*  off_r   = (int*)take((size_t)N * sizeof(int));
    int*  deg_f   = (int*)take((size_t)N * sizeof(int));
    int*  deg_r   = (int*)take((size_t)N * sizeof(int));
    u32*  buf_f   = (u32*)take((size_t)B * SLAB * sizeof(u32));      // 8.0 MB
    u32*  buf_r   = (u32*)take((size_t)B * SLAB * sizeof(u32));      // 8.0 MB
    int*  gcnt_f = gcnt, *gcnt_r = gcnt + B;

    hipMemsetAsync(gcnt, 0, (size_t)2 * B * sizeof(int), stream);
    hipMemsetAsync(h_bf + (size_t)N * D, 0, D * sizeof(bf16), stream); // zero row

    int n4 = N * D / 4;
    k_cast<<<(n4 + 255) / 256, 256, 0, stream>>>(h, h_bf, n4);

    dim3 gbin((E + BIN_CHUNK - 1) / BIN_CHUNK, 2);
    k_bin<<<gbin, 256, 0, stream>>>(rows, cols, gcnt_f, gcnt_r, buf_f, buf_r, E, B);
    dim3 gsort(B, 2);
    k_sort<<<gsort, 256, 0, stream>>>(gcnt_f, gcnt_r, buf_f, buf_r,
                                      off_f, off_r, deg_f, deg_r, N, (u32)N);
    dim3 gagg((N + 3) / 4, 2);
    k_agg<<<gagg, 256, 0, stream>>>(h_bf, off_f, deg_f, buf_f,
                                    off_r, deg_r, buf_r, AH, ATH, N);
    k_gemm<<<B, 256, 0, stream>>>(h_bf, AH, ATH,
                                  Ws_w, W_w, Wt_w,
                                  Ws_b, W_b, Wt_b,
                                  deg_f, deg_r, out, N);
}

// Round 6
// 329.678 us; speedup vs baseline: 8.9917x; 1.0551x over previous
//
#include <hip/hip_runtime.h>

// BiMPNN layer, MI355X. f32 I/O, bf16 MFMA internally.
//   agg  = A  @ (h@W^T  + b)  ==  (A @ h) @ W^T  + deg_out * b   (linearity)
//   aggt = A^T@ (h@Wt^T + bt) ==  (A^T@ h) @ Wt^T + deg_in  * bt
// R6: (a) k_bin copy-out edge-parallel via per-edge bucket tag (was 48 serial
// scalar stores/thread). (b) k_agg quarter-wave dwordx4 gathers: 4 edges per
// wave-inst, pre-scaled indices, lists padded to x4. (c) weights pre-cast to
// bf16 inside k_cast (also writes zero pad row) -> k_gemm stages B like A.

typedef __bf16 bf16;
typedef __bf16 bf16x4 __attribute__((ext_vector_type(4)));
typedef __bf16 bf16x8 __attribute__((ext_vector_type(8)));
typedef float  f32x4  __attribute__((ext_vector_type(4)));
typedef unsigned int u32;
typedef u32 u32x4 __attribute__((ext_vector_type(4)));
typedef unsigned short u16;

#define D 128
#define CAPC 2432      // max real edges/bucket (mean 2046, +8.5 sigma)
#define SLAB 2816      // CAPC + 128*3 pad slots (pad-to-4 worst case)
#define BIN_CHUNK 12544  // 49 * 256 edges per k_bin block

// One kernel: h f32->bf16, zero pad row, weights f32->bf16 ([Ws|W|Wt]).
__global__ void k_cast(const float* __restrict__ h,
                       const float* __restrict__ Ws_w, const float* __restrict__ W_w,
                       const float* __restrict__ Wt_w,
                       bf16* __restrict__ h_bf, bf16* __restrict__ wbf, int n4h) {
    int i = blockIdx.x * 256 + threadIdx.x;
    if (i < n4h) {
        f32x4 v = *(const f32x4*)&h[i * 4];
        bf16x4 o;
        o.x = (bf16)v.x; o.y = (bf16)v.y; o.z = (bf16)v.z; o.w = (bf16)v.w;
        *(bf16x4*)&h_bf[i * 4] = o;
    } else if (i < n4h + 32) {
        int k = i - n4h;
        bf16x4 z; z.x = (bf16)0.f; z.y = (bf16)0.f; z.z = (bf16)0.f; z.w = (bf16)0.f;
        *(bf16x4*)&h_bf[(size_t)n4h * 4 + k * 4] = z;
    } else {
        int k = i - n4h - 32;
        if (k < 12288) {
            const float* src = (k < 4096) ? Ws_w : (k < 8192) ? W_w : Wt_w;
            int kk = k & 4095;
            f32x4 v = *(const f32x4*)&src[kk * 4];
            bf16x4 o;
            o.x = (bf16)v.x; o.y = (bf16)v.y; o.z = (bf16)v.z; o.w = (bf16)v.w;
            *(bf16x4*)&wbf[k * 4] = o;
        }
    }
}

// In-LDS counting sort by bucket, then edge-parallel tagged copy-out.
// blockIdx.y = direction. packed word: (node&127)<<17 | src.
__global__ __launch_bounds__(256) void k_bin(
    const int* __restrict__ rows, const int* __restrict__ cols,
    int* __restrict__ gcnt_f, int* __restrict__ gcnt_r,
    u32* __restrict__ buf_f, u32* __restrict__ buf_r, int E, int B) {
    __shared__ int hist[1024];    // counts -> cursors
    __shared__ int lbase[1024];   // local exclusive base
    __shared__ int gbase[1024];   // global reserved base
    __shared__ int tsum[256];
    __shared__ u32 sorted[BIN_CHUNK];
    __shared__ u16 btag[BIN_CHUNK];
    int t = threadIdx.x;
    int dir = blockIdx.y;
    const int* key = dir ? cols : rows;
    const int* pay = dir ? rows : cols;
    int* gcnt = dir ? gcnt_r : gcnt_f;
    u32* buf  = dir ? buf_r : buf_f;
    int base = blockIdx.x * BIN_CHUNK;

    for (int b = t; b < 1024; b += 256) hist[b] = 0;
    __syncthreads();
    for (int i = 0; i < BIN_CHUNK / 256; ++i) {
        int e = base + i * 256 + t;
        if (e < E) atomicAdd(&hist[key[e] >> 7], 1);
    }
    __syncthreads();
    // two-level exclusive scan over 1024 buckets (4 consecutive per thread)
    int s0 = hist[t * 4], s1 = hist[t * 4 + 1], s2 = hist[t * 4 + 2], s3 = hist[t * 4 + 3];
    tsum[t] = s0 + s1 + s2 + s3;
    __syncthreads();
    for (int o = 1; o < 256; o <<= 1) {
        int v = (t >= o) ? tsum[t - o] : 0;
        __syncthreads();
        tsum[t] += v;
        __syncthreads();
    }
    int run = (t > 0) ? tsum[t - 1] : 0;
    lbase[t * 4]     = run;
    lbase[t * 4 + 1] = run + s0;
    lbase[t * 4 + 2] = run + s0 + s1;
    lbase[t * 4 + 3] = run + s0 + s1 + s2;
    __syncthreads();
    int total = tsum[255];
    for (int b = t; b < 1024; b += 256) {
        int nxt = (b < 1023) ? lbase[b + 1] : total;
        int c = nxt - lbase[b];
        gbase[b] = (c && b < B) ? atomicAdd(&gcnt[b], c) : 0;
        hist[b] = lbase[b];
    }
    __syncthreads();
    for (int i = 0; i < BIN_CHUNK / 256; ++i) {
        int e = base + i * 256 + t;
        if (e < E) {
            int k = key[e], p = pay[e];
            int b = k >> 7;
            int pos = atomicAdd(&hist[b], 1);
            sorted[pos] = ((u32)(k & 127) << 17) | (u32)p;
            btag[pos] = (u16)b;
        }
    }
    __syncthreads();
    // edge-parallel copy-out (coalesced within bucket runs)
    for (int i = t; i < total; i += 256) {
        int b = btag[i];
        int gp = gbase[b] + (i - lbase[b]);
        if (gp < CAPC) buf[(size_t)b * SLAB + gp] = sorted[i];
    }
}

// Per-bucket LDS counting sort by local node (7 bits). Rewrites slab with
// PRE-SCALED src-only words (src<<6 = dword row offset) grouped by node, each
// node's run padded to multiple of 4 with PADV (zero row). Emits off[]/deg[].
__global__ __launch_bounds__(256) void k_sort(
    const int* __restrict__ cnt_f, const int* __restrict__ cnt_r,
    u32* __restrict__ buf_f, u32* __restrict__ buf_r,
    int* __restrict__ off_f, int* __restrict__ off_r,
    int* __restrict__ deg_f, int* __restrict__ deg_r, int N, u32 PADV) {
    __shared__ u32 words[CAPC];
    __shared__ u32 sorted[SLAB];
    __shared__ int hist[128], pscn[128], cur[128];
    int t = threadIdx.x, bkt = blockIdx.x;
    const int* cp; u32* buf; int* off; int* deg;
    if (blockIdx.y == 0) { cp = cnt_f; buf = buf_f + (size_t)bkt * SLAB; off = off_f; deg = deg_f; }
    else                 { cp = cnt_r; buf = buf_r + (size_t)bkt * SLAB; off = off_r; deg = deg_r; }
    int cnt = cp[bkt]; if (cnt > CAPC) cnt = CAPC;
    if (t < 128) hist[t] = 0;
    __syncthreads();
    for (int i = t; i < cnt; i += 256) {
        u32 w = buf[i]; words[i] = w;
        atomicAdd(&hist[w >> 17], 1);
    }
    __syncthreads();
    int pd = 0;
    if (t < 128) { pd = (hist[t] + 3) & ~3; pscn[t] = pd; }
    __syncthreads();
    for (int o = 1; o < 128; o <<= 1) {          // inclusive scan of padded degs
        int v = (t < 128 && t >= o) ? pscn[t - o] : 0;
        __syncthreads();
        if (t < 128) pscn[t] += v;
        __syncthreads();
    }
    int ptot = pscn[127];
    int node0 = bkt * 128;
    if (t < 128) {
        int pstart = pscn[t] - pd;
        cur[t] = pstart;
        int node = node0 + t;
        if (node < N) { off[node] = bkt * SLAB + pstart; deg[node] = hist[t]; }
    }
    __syncthreads();
    for (int i = t; i < ptot; i += 256) sorted[i] = PADV;
    __syncthreads();
    for (int i = t; i < cnt; i += 256) {
        u32 w = words[i];
        int p = atomicAdd(&cur[w >> 17], 1);
        sorted[p] = (w & 0x1FFFF) << 6;          // pre-scaled dword row offset
    }
    __syncthreads();
    for (int i = t; i < ptot; i += 256) buf[i] = sorted[i];
}

__device__ __forceinline__ float blo(u32 w) { return __uint_as_float(w << 16); }
__device__ __forceinline__ float bhi(u32 w) { return __uint_as_float(w & 0xffff0000u); }

// One wave per (node, direction). Quarter-wave: 16 lanes cover one row
// (16B/lane dwordx4) -> 4 edges per wave-inst; lists padded to x4 with PADV.
__global__ void k_agg(const u32* __restrict__ h32,
                      const int* __restrict__ off_f, const int* __restrict__ deg_f,
                      const u32* __restrict__ buf_f,
                      const int* __restrict__ off_r, const int* __restrict__ deg_r,
                      const u32* __restrict__ buf_r,
                      bf16* __restrict__ AH, bf16* __restrict__ ATH, int N) {
    int wave = threadIdx.x >> 6, lane = threadIdx.x & 63;
    int node = blockIdx.x * 4 + wave;
    if (node >= N) return;
    const int* off; const int* deg; const u32* idx; bf16* dst;
    if (blockIdx.y == 0) { off = off_f; deg = deg_f; idx = buf_f; dst = AH; }
    else                 { off = off_r; deg = deg_r; idx = buf_r; dst = ATH; }
    int p = off[node];
    int pend = p + ((deg[node] + 3) & ~3);
    int q = lane >> 4, c = lane & 15;
    float a0 = 0.f, a1 = 0.f, a2 = 0.f, a3 = 0.f;
    float a4 = 0.f, a5 = 0.f, a6 = 0.f, a7 = 0.f;
    for (; p + 15 < pend; p += 16) {
        u32 j0 = idx[p + q], j1 = idx[p + 4 + q];
        u32 j2 = idx[p + 8 + q], j3 = idx[p + 12 + q];
        u32x4 w0 = *(const u32x4*)&h32[(size_t)j0 + c * 4];
        u32x4 w1 = *(const u32x4*)&h32[(size_t)j1 + c * 4];
        u32x4 w2 = *(const u32x4*)&h32[(size_t)j2 + c * 4];
        u32x4 w3 = *(const u32x4*)&h32[(size_t)j3 + c * 4];
        a0 += blo(w0.x); a1 += bhi(w0.x); a2 += blo(w0.y); a3 += bhi(w0.y);
        a4 += blo(w0.z); a5 += bhi(w0.z); a6 += blo(w0.w); a7 += bhi(w0.w);
        a0 += blo(w1.x); a1 += bhi(w1.x); a2 += blo(w1.y); a3 += bhi(w1.y);
        a4 += blo(w1.z); a5 += bhi(w1.z); a6 += blo(w1.w); a7 += bhi(w1.w);
        a0 += blo(w2.x); a1 += bhi(w2.x); a2 += blo(w2.y); a3 += bhi(w2.y);
        a4 += blo(w2.z); a5 += bhi(w2.z); a6 += blo(w2.w); a7 += bhi(w2.w);
        a0 += blo(w3.x); a1 += bhi(w3.x); a2 += blo(w3.y); a3 += bhi(w3.y);
        a4 += blo(w3.z); a5 += bhi(w3.z); a6 += blo(w3.w); a7 += bhi(w3.w);
    }
    for (; p + 3 < pend; p += 4) {
        u32 j = idx[p + q];
        u32x4 w = *(const u32x4*)&h32[(size_t)j + c * 4];
        a0 += blo(w.x); a1 += bhi(w.x); a2 += blo(w.y); a3 += bhi(w.y);
        a4 += blo(w.z); a5 += bhi(w.z); a6 += blo(w.w); a7 += bhi(w.w);
    }
    a0 += __shfl_down(a0, 16); a1 += __shfl_down(a1, 16);
    a2 += __shfl_down(a2, 16); a3 += __shfl_down(a3, 16);
    a4 += __shfl_down(a4, 16); a5 += __shfl_down(a5, 16);
    a6 += __shfl_down(a6, 16); a7 += __shfl_down(a7, 16);
    a0 += __shfl_down(a0, 32); a1 += __shfl_down(a1, 32);
    a2 += __shfl_down(a2, 32); a3 += __shfl_down(a3, 32);
    a4 += __shfl_down(a4, 32); a5 += __shfl_down(a5, 32);
    a6 += __shfl_down(a6, 32); a7 += __shfl_down(a7, 32);
    if (lane < 16) {
        bf16x8 o;
        o[0] = (bf16)a0; o[1] = (bf16)a1; o[2] = (bf16)a2; o[3] = (bf16)a3;
        o[4] = (bf16)a4; o[5] = (bf16)a5; o[6] = (bf16)a6; o[7] = (bf16)a7;
        *(bf16x8*)&dst[(size_t)node * D + c * 8] = o;
    }
}

// Fused GEMM + bias + exact GELU. All-bf16 staging now (weights pre-cast).
__global__ __launch_bounds__(256) void k_gemm(
    const bf16* __restrict__ h, const bf16* __restrict__ AH, const bf16* __restrict__ ATH,
    const bf16* __restrict__ wbf,   // [Ws|W|Wt], each 128x128
    const float* __restrict__ Ws_b, const float* __restrict__ W_b, const float* __restrict__ Wt_b,
    const int* __restrict__ deg_out, const int* __restrict__ deg_in,
    float* __restrict__ out, int N) {
    __shared__ __align__(16) bf16 Ash[128 * 32];
    __shared__ __align__(16) bf16 Bsh[128 * 32];
    int t = threadIdx.x;
    int lane = t & 63;
    int w = t >> 6;
    int wm = (w >> 1) * 64, wn = (w & 1) * 64;
    int m0 = blockIdx.x * 128;

    f32x4 acc[4][4];
#pragma unroll
    for (int i = 0; i < 4; ++i)
#pragma unroll
        for (int j = 0; j < 4; ++j)
            acc[i][j] = (f32x4){0.f, 0.f, 0.f, 0.f};

    for (int kc = 0; kc < 12; ++kc) {
        const bf16* X  = (kc < 4) ? h : (kc < 8) ? AH : ATH;
        const bf16* Wm = wbf + (kc >> 2) * (128 * 128);
        int c0 = (kc & 3) * 32;
#pragma unroll
        for (int r = 0; r < 2; ++r) {
            int v = r * 256 + t;
            int row = v >> 2, seg = v & 3;
            int xr = m0 + row; if (xr >= N) xr = N - 1;  // clamp, stores guarded
            *(bf16x8*)&Ash[row * 32 + seg * 8] =
                *(const bf16x8*)&X[(size_t)xr * D + c0 + seg * 8];
            *(bf16x8*)&Bsh[row * 32 + seg * 8] =
                *(const bf16x8*)&Wm[row * D + c0 + seg * 8];
        }
        __syncthreads();
        int kg = lane >> 4, lr = lane & 15;
        bf16x8 a[4], b[4];
#pragma unroll
        for (int i = 0; i < 4; ++i) {
            a[i] = *(const bf16x8*)&Ash[(wm + i * 16 + lr) * 32 + kg * 8];
            b[i] = *(const bf16x8*)&Bsh[(wn + i * 16 + lr) * 32 + kg * 8];
        }
#pragma unroll
        for (int i = 0; i < 4; ++i)
#pragma unroll
            for (int j = 0; j < 4; ++j)
                acc[i][j] = __builtin_amdgcn_mfma_f32_16x16x32_bf16(
                    a[i], b[j], acc[i][j], 0, 0, 0);
        __syncthreads();
    }

    int lr = lane & 15, lq = lane >> 4;
#pragma unroll
    for (int i = 0; i < 4; ++i) {
#pragma unroll
        for (int r = 0; r < 4; ++r) {
            int node = m0 + wm + i * 16 + lq * 4 + r;
            if (node >= N) continue;
            float fdr = (float)deg_out[node], fdc = (float)deg_in[node];
#pragma unroll
            for (int j = 0; j < 4; ++j) {
                int f = wn + j * 16 + lr;
                float val = acc[i][j][r] + Ws_b[f] + fdr * W_b[f] + fdc * Wt_b[f];
                float g = 0.5f * val * (1.0f + erff(val * 0.70710678118654752f));
                out[(size_t)node * D + f] = g;
            }
        }
    }
}

extern "C" void kernel_launch(void* const* d_in, const int* in_sizes, int n_in,
                              void* d_out, int out_size, void* d_ws, size_t ws_size,
                              hipStream_t stream) {
    const float* h    = (const float*)d_in[0];
    const float* W_w  = (const float*)d_in[1];
    const float* W_b  = (const float*)d_in[2];
    const float* Wt_w = (const float*)d_in[3];
    const float* Wt_b = (const float*)d_in[4];
    const float* Ws_w = (const float*)d_in[5];
    const float* Ws_b = (const float*)d_in[6];
    const int*   rows = (const int*)d_in[7];
    const int*   cols = (const int*)d_in[8];
    float* out = (float*)d_out;

    const int N = in_sizes[0] / D;        // 100000
    const int E = in_sizes[7];            // 1600000
    const int B = (N + 127) >> 7;         // 782 buckets

    char* ws = (char*)d_ws;
    size_t off = 0;
    auto take = [&](size_t bytes) -> char* {
        char* p = ws + off;
        off += (bytes + 511) & ~(size_t)511;
        return p;
    };
    bf16* h_bf    = (bf16*)take((size_t)(N + 1) * D * sizeof(bf16)); // +1 zero row
    bf16* AH      = (bf16*)take((size_t)N * D * sizeof(bf16));
    bf16* ATH     = (bf16*)take((size_t)N * D * sizeof(bf16));
    bf16* wbf     = (bf16*)take((size_t)3 * 128 * 128 * sizeof(bf16));
    int*  gcnt    = (int*)take((size_t)2 * B * sizeof(int));
    int*  off_f   = (int*)take((size_t)N * sizeof(int));
    int*  off_r   = (int*)take((size_t)N * sizeof(int));
    int*  deg_f   = (int*)take((size_t)N * sizeof(int));
    int*  deg_r   = (int*)take((size_t)N * sizeof(int));
    u32*  buf_f   = (u32*)take((size_t)B * SLAB * sizeof(u32));      // 8.8 MB
    u32*  buf_r   = (u32*)take((size_t)B * SLAB * sizeof(u32));      // 8.8 MB
    int*  gcnt_f = gcnt, *gcnt_r = gcnt + B;

    hipMemsetAsync(gcnt, 0, (size_t)2 * B * sizeof(int), stream);

    int n4h = N * D / 4;
    int ncast = n4h + 32 + 3 * 128 * 128 / 4;
    k_cast<<<(ncast + 255) / 256, 256, 0, stream>>>(h, Ws_w, W_w, Wt_w,
                                                    h_bf, wbf, n4h);

    dim3 gbin((E + BIN_CHUNK - 1) / BIN_CHUNK, 2);
    k_bin<<<gbin, 256, 0, stream>>>(rows, cols, gcnt_f, gcnt_r, buf_f, buf_r, E, B);
    dim3 gsort(B, 2);
    k_sort<<<gsort, 256, 0, stream>>>(gcnt_f, gcnt_r, buf_f, buf_r,
                                      off_f, off_r, deg_f, deg_r, N, (u32)N << 6);
    dim3 gagg((N + 3) / 4, 2);
    k_agg<<<gagg, 256, 0, stream>>>((const u32*)h_bf, off_f, deg_f, buf_f,
                                    off_r, deg_r, buf_r, AH, ATH, N);
    k_gemm<<<B, 256, 0, stream>>>(h_bf, AH, ATH, wbf,
                                  Ws_b, W_b, Wt_b,
                                  deg_f, deg_r, out, N);
}

// Round 7
// 317.813 us; speedup vs baseline: 9.3273x; 1.0373x over previous
//
#include <hip/hip_runtime.h>

// BiMPNN layer, MI355X. f32 I/O, bf16 MFMA internally.
//   agg  = A  @ (h@W^T  + b)  ==  (A @ h) @ W^T  + deg_out * b   (linearity)
//   aggt = A^T@ (h@Wt^T + bt) ==  (A^T@ h) @ Wt^T + deg_in  * bt
// R7: 3-launch pipeline. (a) k_bin gains a cast plane (blockIdx.y==2) so the
// h/weights f32->bf16 conversion overlaps binning; chunk 6400 for 2-3 blocks/CU.
// (b) k_aggsort fuses per-bucket LDS counting sort + register aggregation:
// kills the k_sort launch and the sorted-slab writeback/re-read (~40 MB).
// (c) k_gemm unchanged (128x128 tile, 16x16x32 bf16 MFMA, fused bias+GELU).

typedef __bf16 bf16;
typedef __bf16 bf16x4 __attribute__((ext_vector_type(4)));
typedef __bf16 bf16x8 __attribute__((ext_vector_type(8)));
typedef float  f32x4  __attribute__((ext_vector_type(4)));
typedef unsigned int u32;
typedef u32 u32x4 __attribute__((ext_vector_type(4)));
typedef unsigned short u16;

#define D 128
#define CAPC 2432      // max real edges/bucket (mean 2046, +8.5 sigma)
#define SLAB 2816      // CAPC + 128*3 pad slots (pad-to-4 worst case)
#define BIN_CHUNK 6400 // 25 * 256 edges per k_bin block

// Binning (y=0,1) + cast plane (y=2).
// packed word: (node&127)<<17 | src.
__global__ __launch_bounds__(256) void k_bin(
    const int* __restrict__ rows, const int* __restrict__ cols,
    int* __restrict__ gcnt_f, int* __restrict__ gcnt_r,
    u32* __restrict__ buf_f, u32* __restrict__ buf_r, int E, int B,
    const float* __restrict__ h,
    const float* __restrict__ Ws_w, const float* __restrict__ W_w,
    const float* __restrict__ Wt_w,
    bf16* __restrict__ h_bf, bf16* __restrict__ wbf, int n4h) {
    __shared__ int hist[1024];    // counts -> cursors
    __shared__ int lbase[1024];   // local exclusive base
    __shared__ int gbase[1024];   // global reserved base
    __shared__ int tsum[256];
    __shared__ u32 sorted[BIN_CHUNK];
    __shared__ u16 btag[BIN_CHUNK];
    int t = threadIdx.x;

    if (blockIdx.y == 2) {        // ---- cast plane: h->bf16, pad row, weights
        int stride = gridDim.x * 256;
        int ncast = n4h + 32 + 12288;
        for (int i = blockIdx.x * 256 + t; i < ncast; i += stride) {
            if (i < n4h) {
                f32x4 v = *(const f32x4*)&h[i * 4];
                bf16x4 o;
                o.x = (bf16)v.x; o.y = (bf16)v.y; o.z = (bf16)v.z; o.w = (bf16)v.w;
                *(bf16x4*)&h_bf[i * 4] = o;
            } else if (i < n4h + 32) {
                int k = i - n4h;
                bf16x4 z; z.x = (bf16)0.f; z.y = (bf16)0.f; z.z = (bf16)0.f; z.w = (bf16)0.f;
                *(bf16x4*)&h_bf[(size_t)n4h * 4 + k * 4] = z;
            } else {
                int k = i - n4h - 32;
                const float* src = (k < 4096) ? Ws_w : (k < 8192) ? W_w : Wt_w;
                int kk = k & 4095;
                f32x4 v = *(const f32x4*)&src[kk * 4];
                bf16x4 o;
                o.x = (bf16)v.x; o.y = (bf16)v.y; o.z = (bf16)v.z; o.w = (bf16)v.w;
                *(bf16x4*)&wbf[k * 4] = o;
            }
        }
        return;
    }

    int dir = blockIdx.y;
    const int* key = dir ? cols : rows;
    const int* pay = dir ? rows : cols;
    int* gcnt = dir ? gcnt_r : gcnt_f;
    u32* buf  = dir ? buf_r : buf_f;
    int base = blockIdx.x * BIN_CHUNK;

    for (int b = t; b < 1024; b += 256) hist[b] = 0;
    __syncthreads();
    for (int i = 0; i < BIN_CHUNK / 256; ++i) {
        int e = base + i * 256 + t;
        if (e < E) atomicAdd(&hist[key[e] >> 7], 1);
    }
    __syncthreads();
    // two-level exclusive scan over 1024 buckets (4 consecutive per thread)
    int s0 = hist[t * 4], s1 = hist[t * 4 + 1], s2 = hist[t * 4 + 2], s3 = hist[t * 4 + 3];
    tsum[t] = s0 + s1 + s2 + s3;
    __syncthreads();
    for (int o = 1; o < 256; o <<= 1) {
        int v = (t >= o) ? tsum[t - o] : 0;
        __syncthreads();
        tsum[t] += v;
        __syncthreads();
    }
    int run = (t > 0) ? tsum[t - 1] : 0;
    lbase[t * 4]     = run;
    lbase[t * 4 + 1] = run + s0;
    lbase[t * 4 + 2] = run + s0 + s1;
    lbase[t * 4 + 3] = run + s0 + s1 + s2;
    __syncthreads();
    int total = tsum[255];
    for (int b = t; b < 1024; b += 256) {
        int nxt = (b < 1023) ? lbase[b + 1] : total;
        int c = nxt - lbase[b];
        gbase[b] = (c && b < B) ? atomicAdd(&gcnt[b], c) : 0;
        hist[b] = lbase[b];
    }
    __syncthreads();
    for (int i = 0; i < BIN_CHUNK / 256; ++i) {
        int e = base + i * 256 + t;
        if (e < E) {
            int k = key[e], p = pay[e];
            int b = k >> 7;
            int pos = atomicAdd(&hist[b], 1);
            sorted[pos] = ((u32)(k & 127) << 17) | (u32)p;
            btag[pos] = (u16)b;
        }
    }
    __syncthreads();
    // edge-parallel copy-out (coalesced within bucket runs)
    for (int i = t; i < total; i += 256) {
        int b = btag[i];
        int gp = gbase[b] + (i - lbase[b]);
        if (gp < CAPC) buf[(size_t)b * SLAB + gp] = sorted[i];
    }
}

__device__ __forceinline__ float blo(u32 w) { return __uint_as_float(w << 16); }
__device__ __forceinline__ float bhi(u32 w) { return __uint_as_float(w & 0xffff0000u); }

// Fused per-bucket sort + aggregation. One block per (bucket, direction):
// 1) LDS counting sort by local node (7 bits), runs padded to x4 with PADV
//    (pre-scaled zero-row offset); 2) each wave aggregates 32 nodes, reading
//    indices from LDS, gathering h rows quarter-wave (16 lanes x 16B dwordx4,
//    4 edges per wave-inst). Emits AH/ATH (bf16) + deg.
__global__ __launch_bounds__(256) void k_aggsort(
    const u32* __restrict__ h32,
    const int* __restrict__ gcnt_f, const int* __restrict__ gcnt_r,
    const u32* __restrict__ buf_f, const u32* __restrict__ buf_r,
    bf16* __restrict__ AH, bf16* __restrict__ ATH,
    int* __restrict__ deg_f, int* __restrict__ deg_r, int N, u32 PADV) {
    __shared__ u32 words[CAPC];
    __shared__ u32 sorted[SLAB];
    __shared__ int hist[128], pscn[128], cursor[128];
    int t = threadIdx.x, bkt = blockIdx.x;
    const int* cp; const u32* buf; bf16* dst; int* deg;
    if (blockIdx.y == 0) { cp = gcnt_f; buf = buf_f + (size_t)bkt * SLAB; dst = AH;  deg = deg_f; }
    else                 { cp = gcnt_r; buf = buf_r + (size_t)bkt * SLAB; dst = ATH; deg = deg_r; }
    int cnt = cp[bkt]; if (cnt > CAPC) cnt = CAPC;
    if (t < 128) hist[t] = 0;
    __syncthreads();
    for (int i = t; i < cnt; i += 256) {
        u32 w = buf[i]; words[i] = w;
        atomicAdd(&hist[w >> 17], 1);
    }
    __syncthreads();
    int pd = 0;
    if (t < 128) { pd = (hist[t] + 3) & ~3; pscn[t] = pd; }
    __syncthreads();
    for (int o = 1; o < 128; o <<= 1) {          // inclusive scan of padded degs
        int v = (t < 128 && t >= o) ? pscn[t - o] : 0;
        __syncthreads();
        if (t < 128) pscn[t] += v;
        __syncthreads();
    }
    int ptot = pscn[127];
    if (t < 128) cursor[t] = pscn[t] - pd;
    __syncthreads();
    for (int i = t; i < ptot; i += 256) sorted[i] = PADV;
    __syncthreads();
    for (int i = t; i < cnt; i += 256) {
        u32 w = words[i];
        int p = atomicAdd(&cursor[w >> 17], 1);
        sorted[p] = (w & 0x1FFFF) << 6;          // pre-scaled dword row offset
    }
    __syncthreads();

    // ---- aggregation phase: wave per node (32 nodes per wave, sequential)
    int wave = t >> 6, lane = t & 63;
    int q = lane >> 4, c = lane & 15;
    int node0 = bkt * 128;
    for (int ln = wave; ln < 128; ln += 4) {
        int node = node0 + ln;
        if (node >= N) continue;                  // wave-uniform
        int dg = hist[ln];
        int plen = (dg + 3) & ~3;
        int p = pscn[ln] - plen, pend = pscn[ln];
        float a0 = 0.f, a1 = 0.f, a2 = 0.f, a3 = 0.f;
        float a4 = 0.f, a5 = 0.f, a6 = 0.f, a7 = 0.f;
        for (; p + 15 < pend; p += 16) {
            u32 j0 = sorted[p + q],     j1 = sorted[p + 4 + q];
            u32 j2 = sorted[p + 8 + q], j3 = sorted[p + 12 + q];
            u32x4 w0 = *(const u32x4*)&h32[(size_t)j0 + c * 4];
            u32x4 w1 = *(const u32x4*)&h32[(size_t)j1 + c * 4];
            u32x4 w2 = *(const u32x4*)&h32[(size_t)j2 + c * 4];
            u32x4 w3 = *(const u32x4*)&h32[(size_t)j3 + c * 4];
            a0 += blo(w0.x); a1 += bhi(w0.x); a2 += blo(w0.y); a3 += bhi(w0.y);
            a4 += blo(w0.z); a5 += bhi(w0.z); a6 += blo(w0.w); a7 += bhi(w0.w);
            a0 += blo(w1.x); a1 += bhi(w1.x); a2 += blo(w1.y); a3 += bhi(w1.y);
            a4 += blo(w1.z); a5 += bhi(w1.z); a6 += blo(w1.w); a7 += bhi(w1.w);
            a0 += blo(w2.x); a1 += bhi(w2.x); a2 += blo(w2.y); a3 += bhi(w2.y);
            a4 += blo(w2.z); a5 += bhi(w2.z); a6 += blo(w2.w); a7 += bhi(w2.w);
            a0 += blo(w3.x); a1 += bhi(w3.x); a2 += blo(w3.y); a3 += bhi(w3.y);
            a4 += blo(w3.z); a5 += bhi(w3.z); a6 += blo(w3.w); a7 += bhi(w3.w);
        }
        for (; p + 3 < pend; p += 4) {
            u32 j = sorted[p + q];
            u32x4 w = *(const u32x4*)&h32[(size_t)j + c * 4];
            a0 += blo(w.x); a1 += bhi(w.x); a2 += blo(w.y); a3 += bhi(w.y);
            a4 += blo(w.z); a5 += bhi(w.z); a6 += blo(w.w); a7 += bhi(w.w);
        }
        a0 += __shfl_down(a0, 16); a1 += __shfl_down(a1, 16);
        a2 += __shfl_down(a2, 16); a3 += __shfl_down(a3, 16);
        a4 += __shfl_down(a4, 16); a5 += __shfl_down(a5, 16);
        a6 += __shfl_down(a6, 16); a7 += __shfl_down(a7, 16);
        a0 += __shfl_down(a0, 32); a1 += __shfl_down(a1, 32);
        a2 += __shfl_down(a2, 32); a3 += __shfl_down(a3, 32);
        a4 += __shfl_down(a4, 32); a5 += __shfl_down(a5, 32);
        a6 += __shfl_down(a6, 32); a7 += __shfl_down(a7, 32);
        if (lane < 16) {
            bf16x8 o;
            o[0] = (bf16)a0; o[1] = (bf16)a1; o[2] = (bf16)a2; o[3] = (bf16)a3;
            o[4] = (bf16)a4; o[5] = (bf16)a5; o[6] = (bf16)a6; o[7] = (bf16)a7;
            *(bf16x8*)&dst[(size_t)node * D + c * 8] = o;
        }
    }
    if (t < 128) {
        int node = node0 + t;
        if (node < N) deg[node] = hist[t];
    }
}

// Fused GEMM + bias + exact GELU. All-bf16 staging (weights pre-cast).
// A frag lane: m=lane&15, k=(lane>>4)*8+j; B frag same with n; C/D: col=lane&15,
// row=(lane>>4)*4+r. (k-permutation consistent between A and B staging.)
__global__ __launch_bounds__(256) void k_gemm(
    const bf16* __restrict__ h, const bf16* __restrict__ AH, const bf16* __restrict__ ATH,
    const bf16* __restrict__ wbf,   // [Ws|W|Wt], each 128x128
    const float* __restrict__ Ws_b, const float* __restrict__ W_b, const float* __restrict__ Wt_b,
    const int* __restrict__ deg_out, const int* __restrict__ deg_in,
    float* __restrict__ out, int N) {
    __shared__ __align__(16) bf16 Ash[128 * 32];
    __shared__ __align__(16) bf16 Bsh[128 * 32];
    int t = threadIdx.x;
    int lane = t & 63;
    int w = t >> 6;
    int wm = (w >> 1) * 64, wn = (w & 1) * 64;
    int m0 = blockIdx.x * 128;

    f32x4 acc[4][4];
#pragma unroll
    for (int i = 0; i < 4; ++i)
#pragma unroll
        for (int j = 0; j < 4; ++j)
            acc[i][j] = (f32x4){0.f, 0.f, 0.f, 0.f};

    for (int kc = 0; kc < 12; ++kc) {
        const bf16* X  = (kc < 4) ? h : (kc < 8) ? AH : ATH;
        const bf16* Wm = wbf + (kc >> 2) * (128 * 128);
        int c0 = (kc & 3) * 32;
#pragma unroll
        for (int r = 0; r < 2; ++r) {
            int v = r * 256 + t;
            int row = v >> 2, seg = v & 3;
            int xr = m0 + row; if (xr >= N) xr = N - 1;  // clamp, stores guarded
            *(bf16x8*)&Ash[row * 32 + seg * 8] =
                *(const bf16x8*)&X[(size_t)xr * D + c0 + seg * 8];
            *(bf16x8*)&Bsh[row * 32 + seg * 8] =
                *(const bf16x8*)&Wm[row * D + c0 + seg * 8];
        }
        __syncthreads();
        int kg = lane >> 4, lr = lane & 15;
        bf16x8 a[4], b[4];
#pragma unroll
        for (int i = 0; i < 4; ++i) {
            a[i] = *(const bf16x8*)&Ash[(wm + i * 16 + lr) * 32 + kg * 8];
            b[i] = *(const bf16x8*)&Bsh[(wn + i * 16 + lr) * 32 + kg * 8];
        }
#pragma unroll
        for (int i = 0; i < 4; ++i)
#pragma unroll
            for (int j = 0; j < 4; ++j)
                acc[i][j] = __builtin_amdgcn_mfma_f32_16x16x32_bf16(
                    a[i], b[j], acc[i][j], 0, 0, 0);
        __syncthreads();
    }

    int lr = lane & 15, lq = lane >> 4;
#pragma unroll
    for (int i = 0; i < 4; ++i) {
#pragma unroll
        for (int r = 0; r < 4; ++r) {
            int node = m0 + wm + i * 16 + lq * 4 + r;
            if (node >= N) continue;
            float fdr = (float)deg_out[node], fdc = (float)deg_in[node];
#pragma unroll
            for (int j = 0; j < 4; ++j) {
                int f = wn + j * 16 + lr;
                float val = acc[i][j][r] + Ws_b[f] + fdr * W_b[f] + fdc * Wt_b[f];
                float g = 0.5f * val * (1.0f + erff(val * 0.70710678118654752f));
                out[(size_t)node * D + f] = g;
            }
        }
    }
}

extern "C" void kernel_launch(void* const* d_in, const int* in_sizes, int n_in,
                              void* d_out, int out_size, void* d_ws, size_t ws_size,
                              hipStream_t stream) {
    const float* h    = (const float*)d_in[0];
    const float* W_w  = (const float*)d_in[1];
    const float* W_b  = (const float*)d_in[2];
    const float* Wt_w = (const float*)d_in[3];
    const float* Wt_b = (const float*)d_in[4];
    const float* Ws_w = (const float*)d_in[5];
    const float* Ws_b = (const float*)d_in[6];
    const int*   rows = (const int*)d_in[7];
    const int*   cols = (const int*)d_in[8];
    float* out = (float*)d_out;

    const int N = in_sizes[0] / D;        // 100000
    const int E = in_sizes[7];            // 1600000
    const int B = (N + 127) >> 7;         // 782 buckets

    char* ws = (char*)d_ws;
    size_t off = 0;
    auto take = [&](size_t bytes) -> char* {
        char* p = ws + off;
        off += (bytes + 511) & ~(size_t)511;
        return p;
    };
    bf16* h_bf    = (bf16*)take((size_t)(N + 1) * D * sizeof(bf16)); // +1 zero row
    bf16* AH      = (bf16*)take((size_t)N * D * sizeof(bf16));
    bf16* ATH     = (bf16*)take((size_t)N * D * sizeof(bf16));
    bf16* wbf     = (bf16*)take((size_t)3 * 128 * 128 * sizeof(bf16));
    int*  gcnt    = (int*)take((size_t)2 * B * sizeof(int));
    int*  deg_f   = (int*)take((size_t)N * sizeof(int));
    int*  deg_r   = (int*)take((size_t)N * sizeof(int));
    u32*  buf_f   = (u32*)take((size_t)B * SLAB * sizeof(u32));      // 8.8 MB
    u32*  buf_r   = (u32*)take((size_t)B * SLAB * sizeof(u32));      // 8.8 MB
    int*  gcnt_f = gcnt, *gcnt_r = gcnt + B;

    hipMemsetAsync(gcnt, 0, (size_t)2 * B * sizeof(int), stream);

    int n4h = N * D / 4;
    dim3 gbin((E + BIN_CHUNK - 1) / BIN_CHUNK, 3);   // y=0,1: bin dirs; y=2: cast
    k_bin<<<gbin, 256, 0, stream>>>(rows, cols, gcnt_f, gcnt_r, buf_f, buf_r,
                                    E, B, h, Ws_w, W_w, Wt_w, h_bf, wbf, n4h);
    dim3 gagg(B, 2);
    k_aggsort<<<gagg, 256, 0, stream>>>((const u32*)h_bf, gcnt_f, gcnt_r,
                                        buf_f, buf_r, AH, ATH,
                                        deg_f, deg_r, N, (u32)N << 6);
    k_gemm<<<B, 256, 0, stream>>>(h_bf, AH, ATH, wbf,
                                  Ws_b, W_b, Wt_b,
                                  deg_f, deg_r, out, N);
}